// Round 13
// baseline (22.561 us; speedup 1.0000x reference)
//
#include <hip/hip_runtime.h>

#define NCH 64
#define WW  97

typedef float        f32x4  __attribute__((ext_vector_type(4)));
typedef float        f32x4u __attribute__((ext_vector_type(4), aligned(4)));
typedef _Float16     h16x4  __attribute__((ext_vector_type(4)));
typedef _Float16     h16x8  __attribute__((ext_vector_type(8)));
typedef unsigned int u32;
typedef unsigned int u32x2 __attribute__((ext_vector_type(2)));

// Rotation-orbit representatives of (i,j,k) in [0,4)^3 under (i,j,k)->(j,k,i).
// First 4 = diagonal (1-cube) orbits; remaining 20 = 3-cube orbits. (R9-verified.)
__constant__ unsigned char ORBITS[24] = {
  0x00, 0x15, 0x2A, 0x3F,
  0x01, 0x02, 0x03, 0x05, 0x0A, 0x0F,
  0x06, 0x09, 0x07, 0x0D, 0x0B, 0x0E,
  0x16, 0x17, 0x1A, 0x1F, 0x2B, 0x2F,
  0x1B, 0x1E
};

#define TAU_STR 24    // bytes per tile-entry: 16 ids + 8 pad (spreads h across banks)
#define RHO_STR 392   // bytes per row: 16*24 + 8 pad (odd dword count*2; %8==0)

// Orbit-v2: x read from global EXACTLY ONCE (67 MB total traffic).
// Within batch b, x position = (row, tile, off). Output (c,t,u) needs own value
// at (c,t,u) and the bin-id of position (t,u,c). A WG owning the rotation orbit
// {(A,B,C),(B,C,A),(C,A,B)} of 16^3 cubes is closed under this map.
__global__ __launch_bounds__(512)
void pw_kernel(const float* __restrict__ x,
               const float* __restrict__ w,
               float* __restrict__ out) {
  __shared__ h16x4 wexp[NCH * 32];                         // 16 KB monomial f16 coeffs
  __shared__ __align__(8) unsigned char sid[3][16 * RHO_STR];  // 18.4 KB ids

  const int g    = blockIdx.x;
  const int b    = g & 31;          // XCD = g%8 = b%8; each XCD gets full orbit sets
  const int o    = g >> 5;
  const int ob   = ORBITS[o];
  const int nreg = (o < 4) ? 1 : 3;
  const int e0   = ((ob >> 4) & 3) << 4;
  const int e1   = ((ob >> 2) & 3) << 4;
  const int e2   = (ob & 3) << 4;

  const int tid = threadIdx.x;
  const int rho = tid >> 5;          // 0..15  (row-local / c-local)
  const int sig = (tid >> 1) & 15;   // 0..15  (tile-local / t-local)
  const int h   = tid & 1;           // off-half

  // ---- build monomial table from w (R12-identical) ----
  #pragma unroll
  for (int k = 0; k < 2; ++k) {
    const int pr = tid + k * 512;
    const int c  = pr >> 4, k2 = pr & 15;
    const float* wr = w + c * WW + 6 * k2;
    const f32x4u wa = *reinterpret_cast<const f32x4u*>(wr);
    const f32x4u wb = *reinterpret_cast<const f32x4u*>(wr + 3);
    h16x8 hh;
    {
      const float A = wa[3] - wa[0], B = wa[3] + wa[0];
      const float C = wa[1] - wa[2], D = wa[1] + wa[2];
      hh[0] = (_Float16)fmaf(D, 0.5625f, B * -0.0625f);
      hh[1] = (_Float16)fmaf(C, -1.6875f, A * -0.0625f);
      hh[2] = (_Float16)((B - D) * 0.5625f);
      hh[3] = (_Float16)fmaf(C, 1.6875f, A * 0.5625f);
    }
    {
      const float A = wb[3] - wb[0], B = wb[3] + wb[0];
      const float C = wb[1] - wb[2], D = wb[1] + wb[2];
      hh[4] = (_Float16)fmaf(D, 0.5625f, B * -0.0625f);
      hh[5] = (_Float16)fmaf(C, -1.6875f, A * -0.0625f);
      hh[6] = (_Float16)((B - D) * 0.5625f);
      hh[7] = (_Float16)fmaf(C, 1.6875f, A * 0.5625f);
    }
    *reinterpret_cast<h16x8*>(&wexp[(c << 5) + (k2 << 1)]) = hh;
  }

  // ---- phase 1: load region (own values -> regs), pack ids -> LDS ----
  // region r: rows R, tiles T, offs O (each 16-wide). Thread: 8 floats at
  // (R+rho, T+sig, O+8h..+8). sid[r][rho*392 + sig*24 + omega] = id byte.
  auto stage = [&](int r, int R, int T, int O, f32x4& qa, f32x4& qb) {
    const float* p = x + (((size_t)(b * NCH + R + rho)) << 12)
                       + ((T + sig) << 6) + O + 8 * h;
    qa = *reinterpret_cast<const f32x4*>(p);
    qb = *reinterpret_cast<const f32x4*>(p + 4);
    u32 p0 = 0, p1 = 0;
    #pragma unroll
    for (int i = 0; i < 4; ++i) {
      const float t0 = fmaf(qa[i], 16.0f, 16.0f);   // == (x+1)/2*32 bitwise
      int id0 = (int)t0;                             // trunc toward zero
      id0 = id0 < 0 ? 0 : (id0 > 31 ? 31 : id0);
      p0 |= (u32)id0 << (8 * i);
      const float t1 = fmaf(qb[i], 16.0f, 16.0f);
      int id1 = (int)t1;
      id1 = id1 < 0 ? 0 : (id1 > 31 ? 31 : id1);
      p1 |= (u32)id1 << (8 * i);
    }
    u32x2 pv; pv[0] = p0; pv[1] = p1;
    *reinterpret_cast<u32x2*>(&sid[r][rho * RHO_STR + sig * TAU_STR + 8 * h]) = pv;
  };

  f32x4 v0a, v0b, v1a, v1b, v2a, v2b;
  stage(0, e0, e1, e2, v0a, v0b);
  if (nreg == 3) {
    stage(1, e1, e2, e0, v1a, v1b);
    stage(2, e2, e0, e1, v2a, v2b);
  }
  __syncthreads();

  // ---- phase 2: cube n: c in CB, t in TB, u in UB; ids from region m ----
  auto cube = [&](int CB, int TB, int UB, int m, const f32x4& qa, const f32x4& qb) {
    const int c  = CB + rho;
    const int t  = TB + sig;
    const int u0 = UB + 8 * h;
    // source (row=t, tile=u, off=c) -> sid[m][sig*392 + (8h+i)*24 + rho]
    const unsigned char* sp = &sid[m][sig * RHO_STR + 192 * h + (rho & ~3)];
    u32 d[8];
    #pragma unroll
    for (int i = 0; i < 8; ++i)
      d[i] = *reinterpret_cast<const u32*>(sp + i * TAU_STR);
    const int sh = (rho & 3) * 8;
    const int cw = c << 5;

    f32x4 res0, res1;
    #pragma unroll
    for (int i = 0; i < 8; ++i) {
      const float xv = (i < 4) ? qa[i & 3] : qb[i & 3];
      // own bin id -> local coordinate (R12-identical)
      const float tt = fmaf(xv, 16.0f, 16.0f);
      int idm = (int)tt;
      idm = idm < 0 ? 0 : (idm > 31 ? 31 : idm);
      const float xin = fmaf(xv, 32.0f, fmaf((float)idm, -2.0f, 31.0f));

      const int widx = (d[i] >> sh) & 31;
      const h16x4 hc = wexp[cw + widx];
      const float r = fmaf(fmaf(fmaf((float)hc[3], xin, (float)hc[2]), xin,
                                (float)hc[1]), xin, (float)hc[0]);
      if (i < 4) res0[i & 3] = r; else res1[i & 3] = r;
    }
    float* op = out + (((size_t)(b * NCH + c)) << 12) + (t << 6) + u0;
    __builtin_nontemporal_store(res0, reinterpret_cast<f32x4*>(op));
    __builtin_nontemporal_store(res1, reinterpret_cast<f32x4*>(op + 4));
  };

  // cube n consumes region (n+1)%3 (diagonal: region 0)
  cube(e0, e1, e2, (nreg == 1) ? 0 : 1, v0a, v0b);
  if (nreg == 3) {
    cube(e1, e2, e0, 2, v1a, v1b);
    cube(e2, e0, e1, 0, v2a, v2b);
  }
}

extern "C" void kernel_launch(void* const* d_in, const int* in_sizes, int n_in,
                              void* d_out, int out_size, void* d_ws, size_t ws_size,
                              hipStream_t stream) {
  const float* x = (const float*)d_in[0];
  const float* w = (const float*)d_in[1];
  float* out    = (float*)d_out;
  pw_kernel<<<dim3(24 * 32), 512, 0, stream>>>(x, w, out);
}